// Round 15
// baseline (301.838 us; speedup 1.0000x reference)
//
#include <hip/hip_runtime.h>
#include <hip/hip_fp16.h>
#include <cfloat>

#define NA 4096
#define NF 256
#define NH 8
#define DH 32
#define KSPLIT 4
#define CHUNK (NA / KSPLIT)    // 1024 keys per block
#define QBLK 32

typedef _Float16 half8_t __attribute__((ext_vector_type(8)));
typedef _Float16 half4_t __attribute__((ext_vector_type(4)));
typedef float f32x4 __attribute__((ext_vector_type(4)));
typedef float f32x8 __attribute__((ext_vector_type(8)));
typedef unsigned long long u64;
typedef unsigned long long u64x2 __attribute__((ext_vector_type(2)));

// log2(e) / sqrt(2*DH) : folds 1/TP and natural->base2 exp into Q scale
#define QSCALE 0.1803368800112723f

// ---------------- pack mask: pm[q][G][j] (u64), bit l = mask[q][G*256+4l+j] --
__global__ __launch_bounds__(512) void pack_mask(
    const int* __restrict__ mask, u64* __restrict__ pm) {
  const int q = blockIdx.x * 8 + (threadIdx.x >> 6);
  const int lane = threadIdx.x & 63;
  const int4* rowv = (const int4*)(mask + (size_t)q * NA);
  u64* dst = pm + (size_t)q * 64;
  for (int G = 0; G < 16; ++G) {
    int4 v = rowv[G * 64 + lane];
    u64 b0 = __ballot(v.x != 0);
    u64 b1 = __ballot(v.y != 0);
    u64 b2 = __ballot(v.z != 0);
    u64 b3 = __ballot(v.w != 0);
    if (lane == 0) {
      u64x2 lo = { b0, b1 };
      u64x2 hi = { b2, b3 };
      *(u64x2*)(dst + G * 4) = lo;
      *(u64x2*)(dst + G * 4 + 2) = hi;
    }
  }
}

// ---------------- QKV projection with fused f32->f16 cast ----------------
// grid (256 m-tiles, 12 = 4 nb x 3 mat), 256 thr = 4 waves; wave owns 16x16.
// Reads x/W as f32, converts in-register. Q,K head-major [h][token][32];
// Q pre-scaled. V transposed Vt[n][token].
__global__ __launch_bounds__(256) void proj_gemm(
    const float* __restrict__ x,
    const float* __restrict__ wq, const float* __restrict__ wk,
    const float* __restrict__ wv,
    const float* __restrict__ bq, const float* __restrict__ bk,
    const float* __restrict__ bv,
    _Float16* __restrict__ Qh, _Float16* __restrict__ Kh,
    _Float16* __restrict__ Vt) {
  const int lane = threadIdx.x & 63;
  const int lr = lane & 15;
  const int lg = lane >> 4;
  const int lg4 = lg * 4;
  const int m0 = blockIdx.x * 16;
  const int mat = blockIdx.y >> 2;
  const int n0 = (blockIdx.y & 3) * 64 + (threadIdx.x >> 6) * 16;
  const float* W = (mat == 0) ? wq : (mat == 1) ? wk : wv;
  const float* bias = (mat == 0) ? bq : (mat == 1) ? bk : bv;

  f32x4 acc = {0.f, 0.f, 0.f, 0.f};
#pragma unroll
  for (int k0 = 0; k0 < NF; k0 += 32) {
    f32x8 af = *(const f32x8*)(x + (size_t)(m0 + lr) * NF + k0 + lg * 8);
    f32x8 bf = *(const f32x8*)(W + (size_t)(n0 + lr) * NF + k0 + lg * 8);
    half8_t afrag, bfrag;
#pragma unroll
    for (int i = 0; i < 8; ++i) { afrag[i] = (_Float16)af[i]; bfrag[i] = (_Float16)bf[i]; }
    acc = __builtin_amdgcn_mfma_f32_16x16x32_f16(afrag, bfrag, acc, 0, 0, 0);
  }
  const int n = n0 + lr;           // C col = lane&15
  const float b = bias[n];
  const int hh = n >> 5;
  const int dd = n & 31;
  if (mat == 0) {
#pragma unroll
    for (int j = 0; j < 4; j++)
      Qh[((size_t)hh * NA + m0 + lg4 + j) * DH + dd] =
          (_Float16)((acc[j] + b) * QSCALE);
  } else if (mat == 1) {
#pragma unroll
    for (int j = 0; j < 4; j++)
      Kh[((size_t)hh * NA + m0 + lg4 + j) * DH + dd] =
          (_Float16)(acc[j] + b);
  } else {
    half4_t hv = { (_Float16)(acc[0] + b), (_Float16)(acc[1] + b),
                   (_Float16)(acc[2] + b), (_Float16)(acc[3] + b) };
    *(half4_t*)(Vt + (size_t)n * NA + m0 + lg4) = hv;
  }
}

// ---------------- flash attention: QBLK=32, key-split, fixed-shift softmax --
// grid = (128 q-tiles, KSPLIT), 512 thr = 8 waves = 8 heads. Two q-halves
// (A: q0+lq, B: q0+16+lq) share K frags, V LDS stage, and barriers ->
// per-score load/barrier overhead and K/V L2 traffic halved vs QBLK=16.
__global__ __launch_bounds__(512, 4) void attn_kernel(
    const _Float16* __restrict__ Qh, const _Float16* __restrict__ Kh,
    const _Float16* __restrict__ Vt, const u64* __restrict__ pm,
    float* __restrict__ part, float* __restrict__ sbuf) {
  __shared__ _Float16 vlds[256 * 64];   // 32 KB
  const int tid = threadIdx.x;
  const int h = tid >> 6;
  const int lane = tid & 63;
  const int lq = lane & 15;
  const int lg = lane >> 4;
  const int q0 = blockIdx.x * QBLK;
  const int kb = blockIdx.y;
  const int k0 = kb * CHUNK;

  const half8_t qfA = *(const half8_t*)(Qh + ((size_t)h * NA + q0 + lq) * DH + lg * 8);
  const half8_t qfB = *(const half8_t*)(Qh + ((size_t)h * NA + q0 + 16 + lq) * DH + lg * 8);
  const _Float16* Kb = Kh + ((size_t)h * NA + k0) * DH;
  const u64* pmA = pm + (size_t)(q0 + lq) * 64 + kb * 16;
  const u64* pmB = pm + (size_t)(q0 + 16 + lq) * 64 + kb * 16;

  // V staging (block-cooperative, granule pre-swizzle keeps LDS linear)
  const int str = tid >> 3;
  const int gx = (tid & 7) ^ (str & 7);
  const _Float16* Vp0 = Vt + (size_t)str * NA + k0 + gx * 8;
  const int wr = str * 64 + (tid & 7) * 8;

  int ro[2][4];
#pragma unroll
  for (int u = 0; u < 2; ++u)
#pragma unroll
    for (int t = 0; t < 4; ++t)
      ro[u][t] = (h * DH + u * 16 + lq) * 64 +
                 (((2 * t + (lg >> 1)) ^ (lq & 7)) << 3) + (lg & 1) * 4;

  const int sh0 = lg, sh1 = lg + 4, sh2 = lg + 8, sh3 = lg + 12;

  f32x4 z = {0.f, 0.f, 0.f, 0.f};
  f32x4 oA0 = z, oA1 = z, oB0 = z, oB1 = z;
  float srA = 0.f, srB = 0.f;

  for (int Gc = 0; Gc < 4; ++Gc) {
    u64x2 waA = *(const u64x2*)(pmA + Gc * 4);
    u64x2 wbA = *(const u64x2*)(pmA + Gc * 4 + 2);
    u64x2 waB = *(const u64x2*)(pmB + Gc * 4);
    u64x2 wbB = *(const u64x2*)(pmB + Gc * 4 + 2);
#pragma unroll
    for (int s = 0; s < 4; ++s) {
      const int kt = Gc * 256 + s * 64;
      // 1) V-stage loads early
      half8_t vg0 = *(const half8_t*)(Vp0 + kt);
      half8_t vg1 = *(const half8_t*)(Vp0 + (size_t)64 * NA + kt);
      half8_t vg2 = *(const half8_t*)(Vp0 + (size_t)128 * NA + kt);
      half8_t vg3 = *(const half8_t*)(Vp0 + (size_t)192 * NA + kt);

      // 2) K frags (shared by both q-halves) + 8 QK MFMAs
      half8_t kf0 = *(const half8_t*)(Kb + (size_t)(kt + 0 * 16 + lq) * DH + lg * 8);
      half8_t kf1 = *(const half8_t*)(Kb + (size_t)(kt + 1 * 16 + lq) * DH + lg * 8);
      half8_t kf2 = *(const half8_t*)(Kb + (size_t)(kt + 2 * 16 + lq) * DH + lg * 8);
      half8_t kf3 = *(const half8_t*)(Kb + (size_t)(kt + 3 * 16 + lq) * DH + lg * 8);
      f32x4 sA0 = __builtin_amdgcn_mfma_f32_16x16x32_f16(kf0, qfA, z, 0, 0, 0);
      f32x4 sA1 = __builtin_amdgcn_mfma_f32_16x16x32_f16(kf1, qfA, z, 0, 0, 0);
      f32x4 sA2 = __builtin_amdgcn_mfma_f32_16x16x32_f16(kf2, qfA, z, 0, 0, 0);
      f32x4 sA3 = __builtin_amdgcn_mfma_f32_16x16x32_f16(kf3, qfA, z, 0, 0, 0);
      f32x4 sB0 = __builtin_amdgcn_mfma_f32_16x16x32_f16(kf0, qfB, z, 0, 0, 0);
      f32x4 sB1 = __builtin_amdgcn_mfma_f32_16x16x32_f16(kf1, qfB, z, 0, 0, 0);
      f32x4 sB2 = __builtin_amdgcn_mfma_f32_16x16x32_f16(kf2, qfB, z, 0, 0, 0);
      f32x4 sB3 = __builtin_amdgcn_mfma_f32_16x16x32_f16(kf3, qfB, z, 0, 0, 0);

      // 3) mask slices
      const unsigned mA0 = (unsigned)(waA[0] >> (16 * s));
      const unsigned mA1 = (unsigned)(waA[1] >> (16 * s));
      const unsigned mA2 = (unsigned)(wbA[0] >> (16 * s));
      const unsigned mA3 = (unsigned)(wbA[1] >> (16 * s));
      const unsigned mB0 = (unsigned)(waB[0] >> (16 * s));
      const unsigned mB1 = (unsigned)(waB[1] >> (16 * s));
      const unsigned mB2 = (unsigned)(wbB[0] >> (16 * s));
      const unsigned mB3 = (unsigned)(wbB[1] >> (16 * s));

      // 4) p = exp2(score), masked -> 0 (fixed-shift softmax)
      f32x4 eA0, eA1, eA2, eA3, eB0, eB1, eB2, eB3;
      eA0[0] = ((mA0 >> sh0) & 1) ? 0.f : __builtin_exp2f(sA0[0]);
      eA0[1] = ((mA1 >> sh0) & 1) ? 0.f : __builtin_exp2f(sA0[1]);
      eA0[2] = ((mA2 >> sh0) & 1) ? 0.f : __builtin_exp2f(sA0[2]);
      eA0[3] = ((mA3 >> sh0) & 1) ? 0.f : __builtin_exp2f(sA0[3]);
      eA1[0] = ((mA0 >> sh1) & 1) ? 0.f : __builtin_exp2f(sA1[0]);
      eA1[1] = ((mA1 >> sh1) & 1) ? 0.f : __builtin_exp2f(sA1[1]);
      eA1[2] = ((mA2 >> sh1) & 1) ? 0.f : __builtin_exp2f(sA1[2]);
      eA1[3] = ((mA3 >> sh1) & 1) ? 0.f : __builtin_exp2f(sA1[3]);
      eA2[0] = ((mA0 >> sh2) & 1) ? 0.f : __builtin_exp2f(sA2[0]);
      eA2[1] = ((mA1 >> sh2) & 1) ? 0.f : __builtin_exp2f(sA2[1]);
      eA2[2] = ((mA2 >> sh2) & 1) ? 0.f : __builtin_exp2f(sA2[2]);
      eA2[3] = ((mA3 >> sh2) & 1) ? 0.f : __builtin_exp2f(sA2[3]);
      eA3[0] = ((mA0 >> sh3) & 1) ? 0.f : __builtin_exp2f(sA3[0]);
      eA3[1] = ((mA1 >> sh3) & 1) ? 0.f : __builtin_exp2f(sA3[1]);
      eA3[2] = ((mA2 >> sh3) & 1) ? 0.f : __builtin_exp2f(sA3[2]);
      eA3[3] = ((mA3 >> sh3) & 1) ? 0.f : __builtin_exp2f(sA3[3]);
      eB0[0] = ((mB0 >> sh0) & 1) ? 0.f : __builtin_exp2f(sB0[0]);
      eB0[1] = ((mB1 >> sh0) & 1) ? 0.f : __builtin_exp2f(sB0[1]);
      eB0[2] = ((mB2 >> sh0) & 1) ? 0.f : __builtin_exp2f(sB0[2]);
      eB0[3] = ((mB3 >> sh0) & 1) ? 0.f : __builtin_exp2f(sB0[3]);
      eB1[0] = ((mB0 >> sh1) & 1) ? 0.f : __builtin_exp2f(sB1[0]);
      eB1[1] = ((mB1 >> sh1) & 1) ? 0.f : __builtin_exp2f(sB1[1]);
      eB1[2] = ((mB2 >> sh1) & 1) ? 0.f : __builtin_exp2f(sB1[2]);
      eB1[3] = ((mB3 >> sh1) & 1) ? 0.f : __builtin_exp2f(sB1[3]);
      eB2[0] = ((mB0 >> sh2) & 1) ? 0.f : __builtin_exp2f(sB2[0]);
      eB2[1] = ((mB1 >> sh2) & 1) ? 0.f : __builtin_exp2f(sB2[1]);
      eB2[2] = ((mB2 >> sh2) & 1) ? 0.f : __builtin_exp2f(sB2[2]);
      eB2[3] = ((mB3 >> sh2) & 1) ? 0.f : __builtin_exp2f(sB2[3]);
      eB3[0] = ((mB0 >> sh3) & 1) ? 0.f : __builtin_exp2f(sB3[0]);
      eB3[1] = ((mB1 >> sh3) & 1) ? 0.f : __builtin_exp2f(sB3[1]);
      eB3[2] = ((mB2 >> sh3) & 1) ? 0.f : __builtin_exp2f(sB3[2]);
      eB3[3] = ((mB3 >> sh3) & 1) ? 0.f : __builtin_exp2f(sB3[3]);

      srA += (eA0[0] + eA0[1] + eA0[2] + eA0[3]) + (eA1[0] + eA1[1] + eA1[2] + eA1[3])
           + (eA2[0] + eA2[1] + eA2[2] + eA2[3]) + (eA3[0] + eA3[1] + eA3[2] + eA3[3]);
      srB += (eB0[0] + eB0[1] + eB0[2] + eB0[3]) + (eB1[0] + eB1[1] + eB1[2] + eB1[3])
           + (eB2[0] + eB2[1] + eB2[2] + eB2[3]) + (eB3[0] + eB3[1] + eB3[2] + eB3[3]);

      half4_t pA0 = { (_Float16)eA0[0], (_Float16)eA0[1], (_Float16)eA0[2], (_Float16)eA0[3] };
      half4_t pA1 = { (_Float16)eA1[0], (_Float16)eA1[1], (_Float16)eA1[2], (_Float16)eA1[3] };
      half4_t pA2 = { (_Float16)eA2[0], (_Float16)eA2[1], (_Float16)eA2[2], (_Float16)eA2[3] };
      half4_t pA3 = { (_Float16)eA3[0], (_Float16)eA3[1], (_Float16)eA3[2], (_Float16)eA3[3] };
      half4_t pB0 = { (_Float16)eB0[0], (_Float16)eB0[1], (_Float16)eB0[2], (_Float16)eB0[3] };
      half4_t pB1 = { (_Float16)eB1[0], (_Float16)eB1[1], (_Float16)eB1[2], (_Float16)eB1[3] };
      half4_t pB2 = { (_Float16)eB2[0], (_Float16)eB2[1], (_Float16)eB2[2], (_Float16)eB2[3] };
      half4_t pB3 = { (_Float16)eB3[0], (_Float16)eB3[1], (_Float16)eB3[2], (_Float16)eB3[3] };

      // 5) commit V to LDS
      *(half8_t*)&vlds[wr]         = vg0;
      *(half8_t*)&vlds[wr + 4096]  = vg1;
      *(half8_t*)&vlds[wr + 8192]  = vg2;
      *(half8_t*)&vlds[wr + 12288] = vg3;
      __syncthreads();

      // 6) PV for both halves: V frags shared
      half4_t va, vb;
      va = *(const half4_t*)&vlds[ro[0][0]]; vb = *(const half4_t*)&vlds[ro[1][0]];
      oA0 = __builtin_amdgcn_mfma_f32_16x16x16f16(va, pA0, oA0, 0, 0, 0);
      oA1 = __builtin_amdgcn_mfma_f32_16x16x16f16(vb, pA0, oA1, 0, 0, 0);
      oB0 = __builtin_amdgcn_mfma_f32_16x16x16f16(va, pB0, oB0, 0, 0, 0);
      oB1 = __builtin_amdgcn_mfma_f32_16x16x16f16(vb, pB0, oB1, 0, 0, 0);
      va = *(const half4_t*)&vlds[ro[0][1]]; vb = *(const half4_t*)&vlds[ro[1][1]];
      oA0 = __builtin_amdgcn_mfma_f32_16x16x16f16(va, pA1, oA0, 0, 0, 0);
      oA1 = __builtin_amdgcn_mfma_f32_16x16x16f16(vb, pA1, oA1, 0, 0, 0);
      oB0 = __builtin_amdgcn_mfma_f32_16x16x16f16(va, pB1, oB0, 0, 0, 0);
      oB1 = __builtin_amdgcn_mfma_f32_16x16x16f16(vb, pB1, oB1, 0, 0, 0);
      va = *(const half4_t*)&vlds[ro[0][2]]; vb = *(const half4_t*)&vlds[ro[1][2]];
      oA0 = __builtin_amdgcn_mfma_f32_16x16x16f16(va, pA2, oA0, 0, 0, 0);
      oA1 = __builtin_amdgcn_mfma_f32_16x16x16f16(vb, pA2, oA1, 0, 0, 0);
      oB0 = __builtin_amdgcn_mfma_f32_16x16x16f16(va, pB2, oB0, 0, 0, 0);
      oB1 = __builtin_amdgcn_mfma_f32_16x16x16f16(vb, pB2, oB1, 0, 0, 0);
      va = *(const half4_t*)&vlds[ro[0][3]]; vb = *(const half4_t*)&vlds[ro[1][3]];
      oA0 = __builtin_amdgcn_mfma_f32_16x16x16f16(va, pA3, oA0, 0, 0, 0);
      oA1 = __builtin_amdgcn_mfma_f32_16x16x16f16(vb, pA3, oA1, 0, 0, 0);
      oB0 = __builtin_amdgcn_mfma_f32_16x16x16f16(va, pB3, oB0, 0, 0, 0);
      oB1 = __builtin_amdgcn_mfma_f32_16x16x16f16(vb, pB3, oB1, 0, 0, 0);
      __syncthreads();
    }
  }

  srA += __shfl_xor(srA, 16); srA += __shfl_xor(srA, 32);
  srB += __shfl_xor(srB, 16); srB += __shfl_xor(srB, 32);

  const int pb = (blockIdx.x * KSPLIT + kb) * NH + h;
  float* pp = part + (size_t)pb * 1024 + lane * 8;
  *(float4*)(pp)           = (float4){ oA0[0], oA0[1], oA0[2], oA0[3] };
  *(float4*)(pp + 4)       = (float4){ oA1[0], oA1[1], oA1[2], oA1[3] };
  *(float4*)(pp + 512)     = (float4){ oB0[0], oB0[1], oB0[2], oB0[3] };
  *(float4*)(pp + 516)     = (float4){ oB1[0], oB1[1], oB1[2], oB1[3] };
  if (lg == 0) {
    sbuf[pb * 32 + lq] = srA;
    sbuf[pb * 32 + 16 + lq] = srB;
  }
}

// ---------------- combine: plain sums over KSPLIT, both q-halves ------------
__global__ __launch_bounds__(256) void combine_kernel(
    const float* __restrict__ part, const float* __restrict__ sbuf,
    float* __restrict__ out) {
  const int wave = blockIdx.x * 4 + (threadIdx.x >> 6);  // qt*NH + h
  const int qt = wave >> 3;
  const int h = wave & 7;
  const int lane = threadIdx.x & 63;
  const int lq = lane & 15;
  const int lg = lane >> 4;

  float SA = 0.f, SB = 0.f;
  float4 A0 = {0,0,0,0}, A1 = {0,0,0,0}, B0 = {0,0,0,0}, B1 = {0,0,0,0};
#pragma unroll
  for (int kb = 0; kb < KSPLIT; kb++) {
    const int pb = (qt * KSPLIT + kb) * NH + h;
    const float* pp = part + (size_t)pb * 1024 + lane * 8;
    float4 a0 = *(const float4*)(pp);
    float4 a1 = *(const float4*)(pp + 4);
    float4 b0 = *(const float4*)(pp + 512);
    float4 b1 = *(const float4*)(pp + 516);
    SA += sbuf[pb * 32 + lq];
    SB += sbuf[pb * 32 + 16 + lq];
    A0.x += a0.x; A0.y += a0.y; A0.z += a0.z; A0.w += a0.w;
    A1.x += a1.x; A1.y += a1.y; A1.z += a1.z; A1.w += a1.w;
    B0.x += b0.x; B0.y += b0.y; B0.z += b0.z; B0.w += b0.w;
    B1.x += b1.x; B1.y += b1.y; B1.z += b1.z; B1.w += b1.w;
  }
  const float iA = 1.f / SA, iB = 1.f / SB;
  float* rowA = out + (size_t)(qt * QBLK + lq) * NF + h * DH;
  float* rowB = out + (size_t)(qt * QBLK + 16 + lq) * NF + h * DH;
  *(float4*)(rowA + lg * 4)      = (float4){ A0.x * iA, A0.y * iA, A0.z * iA, A0.w * iA };
  *(float4*)(rowA + 16 + lg * 4) = (float4){ A1.x * iA, A1.y * iA, A1.z * iA, A1.w * iA };
  *(float4*)(rowB + lg * 4)      = (float4){ B0.x * iB, B0.y * iB, B0.z * iB, B0.w * iB };
  *(float4*)(rowB + 16 + lg * 4) = (float4){ B1.x * iB, B1.y * iB, B1.z * iB, B1.w * iB };
}

extern "C" void kernel_launch(void* const* d_in, const int* in_sizes, int n_in,
                              void* d_out, int out_size, void* d_ws, size_t ws_size,
                              hipStream_t stream) {
  const float* x  = (const float*)d_in[0];
  const int* mask = (const int*)d_in[1];
  const float* Wq = (const float*)d_in[2];
  const float* bq = (const float*)d_in[3];
  const float* Wk = (const float*)d_in[4];
  const float* bk = (const float*)d_in[5];
  const float* Wv = (const float*)d_in[6];
  const float* bv = (const float*)d_in[7];
  float* out = (float*)d_out;

  char* ws = (char*)d_ws;   // ~25.7 MB
  u64* pm       = (u64*)(ws + 0);             // 4096*64*8 = 2 MB
  _Float16* Qh  = (_Float16*)(ws + 2097152);  // [8][4096][32] f16, pre-scaled
  _Float16* Kh  = (_Float16*)(ws + 4194304);  // [8][4096][32] f16
  _Float16* Vt  = (_Float16*)(ws + 6291456);  // [256][4096] f16 (V^T)
  float* part   = (float*)(ws + 8388608);     // 4096 * 1024 f32 = 16 MB
  float* sbuf   = (float*)(ws + 25165824);    // 4096 * 32 f32 = 512 KB

  proj_gemm<<<dim3(256, 12), 256, 0, stream>>>(x, Wq, Wk, Wv, bq, bk, bv,
                                               Qh, Kh, Vt);
  pack_mask<<<512, 512, 0, stream>>>(mask, pm);
  attn_kernel<<<dim3(NA / QBLK, KSPLIT), 512, 0, stream>>>(Qh, Kh, Vt, pm,
                                                           part, sbuf);
  combine_kernel<<<256, 256, 0, stream>>>(part, sbuf, out);
}

// Round 16
// 240.483 us; speedup vs baseline: 1.2551x; 1.2551x over previous
//
#include <hip/hip_runtime.h>
#include <hip/hip_fp16.h>
#include <cfloat>

#define NA 4096
#define NF 256
#define NH 8
#define DH 32
#define KSPLIT 4
#define CHUNK (NA / KSPLIT)    // 1024 keys per block
#define QBLK 32

typedef _Float16 half8_t __attribute__((ext_vector_type(8)));
typedef _Float16 half4_t __attribute__((ext_vector_type(4)));
typedef float f32x4 __attribute__((ext_vector_type(4)));
typedef float f32x8 __attribute__((ext_vector_type(8)));
typedef unsigned long long u64;
typedef unsigned long long u64x2 __attribute__((ext_vector_type(2)));

// log2(e) / sqrt(2*DH) : folds 1/TP and natural->base2 exp into Q scale
#define QSCALE 0.1803368800112723f

// ---------------- pack mask: pm[q][G][j] (u64), bit l = mask[q][G*256+4l+j] --
__global__ __launch_bounds__(512) void pack_mask(
    const int* __restrict__ mask, u64* __restrict__ pm) {
  const int q = blockIdx.x * 8 + (threadIdx.x >> 6);
  const int lane = threadIdx.x & 63;
  const int4* rowv = (const int4*)(mask + (size_t)q * NA);
  u64* dst = pm + (size_t)q * 64;
  for (int G = 0; G < 16; ++G) {
    int4 v = rowv[G * 64 + lane];
    u64 b0 = __ballot(v.x != 0);
    u64 b1 = __ballot(v.y != 0);
    u64 b2 = __ballot(v.z != 0);
    u64 b3 = __ballot(v.w != 0);
    if (lane == 0) {
      u64x2 lo = { b0, b1 };
      u64x2 hi = { b2, b3 };
      *(u64x2*)(dst + G * 4) = lo;
      *(u64x2*)(dst + G * 4 + 2) = hi;
    }
  }
}

// ---------------- QKV projection with fused f32->f16 cast ----------------
__global__ __launch_bounds__(256) void proj_gemm(
    const float* __restrict__ x,
    const float* __restrict__ wq, const float* __restrict__ wk,
    const float* __restrict__ wv,
    const float* __restrict__ bq, const float* __restrict__ bk,
    const float* __restrict__ bv,
    _Float16* __restrict__ Qh, _Float16* __restrict__ Kh,
    _Float16* __restrict__ Vt) {
  const int lane = threadIdx.x & 63;
  const int lr = lane & 15;
  const int lg = lane >> 4;
  const int lg4 = lg * 4;
  const int m0 = blockIdx.x * 16;
  const int mat = blockIdx.y >> 2;
  const int n0 = (blockIdx.y & 3) * 64 + (threadIdx.x >> 6) * 16;
  const float* W = (mat == 0) ? wq : (mat == 1) ? wk : wv;
  const float* bias = (mat == 0) ? bq : (mat == 1) ? bk : bv;

  f32x4 acc = {0.f, 0.f, 0.f, 0.f};
#pragma unroll
  for (int k0 = 0; k0 < NF; k0 += 32) {
    f32x8 af = *(const f32x8*)(x + (size_t)(m0 + lr) * NF + k0 + lg * 8);
    f32x8 bf = *(const f32x8*)(W + (size_t)(n0 + lr) * NF + k0 + lg * 8);
    half8_t afrag, bfrag;
#pragma unroll
    for (int i = 0; i < 8; ++i) { afrag[i] = (_Float16)af[i]; bfrag[i] = (_Float16)bf[i]; }
    acc = __builtin_amdgcn_mfma_f32_16x16x32_f16(afrag, bfrag, acc, 0, 0, 0);
  }
  const int n = n0 + lr;
  const float b = bias[n];
  const int hh = n >> 5;
  const int dd = n & 31;
  if (mat == 0) {
#pragma unroll
    for (int j = 0; j < 4; j++)
      Qh[((size_t)hh * NA + m0 + lg4 + j) * DH + dd] =
          (_Float16)((acc[j] + b) * QSCALE);
  } else if (mat == 1) {
#pragma unroll
    for (int j = 0; j < 4; j++)
      Kh[((size_t)hh * NA + m0 + lg4 + j) * DH + dd] =
          (_Float16)(acc[j] + b);
  } else {
    half4_t hv = { (_Float16)(acc[0] + b), (_Float16)(acc[1] + b),
                   (_Float16)(acc[2] + b), (_Float16)(acc[3] + b) };
    *(half4_t*)(Vt + (size_t)n * NA + m0 + lg4) = hv;
  }
}

// One 16-key subtile: 2 MFMAs -> mask+exp2+sum -> f16 p-frags (transients die)
#define QK_SUBTILE(T, PA, PB)                                                  \
  {                                                                            \
    half8_t kf = *(const half8_t*)(Kb + (size_t)(kt + T * 16 + lq) * DH + lg * 8); \
    f32x4 sA = __builtin_amdgcn_mfma_f32_16x16x32_f16(kf, qfA, z, 0, 0, 0);    \
    f32x4 sB = __builtin_amdgcn_mfma_f32_16x16x32_f16(kf, qfB, z, 0, 0, 0);    \
    const int sh = 16 * s + 4 * T + lg;                                        \
    f32x4 eA, eB;                                                              \
    eA[0] = ((unsigned)(w0A >> sh) & 1) ? 0.f : __builtin_exp2f(sA[0]);        \
    eA[1] = ((unsigned)(w1A >> sh) & 1) ? 0.f : __builtin_exp2f(sA[1]);        \
    eA[2] = ((unsigned)(w2A >> sh) & 1) ? 0.f : __builtin_exp2f(sA[2]);        \
    eA[3] = ((unsigned)(w3A >> sh) & 1) ? 0.f : __builtin_exp2f(sA[3]);        \
    eB[0] = ((unsigned)(w0B >> sh) & 1) ? 0.f : __builtin_exp2f(sB[0]);        \
    eB[1] = ((unsigned)(w1B >> sh) & 1) ? 0.f : __builtin_exp2f(sB[1]);        \
    eB[2] = ((unsigned)(w2B >> sh) & 1) ? 0.f : __builtin_exp2f(sB[2]);        \
    eB[3] = ((unsigned)(w3B >> sh) & 1) ? 0.f : __builtin_exp2f(sB[3]);        \
    srA += (eA[0] + eA[1]) + (eA[2] + eA[3]);                                  \
    srB += (eB[0] + eB[1]) + (eB[2] + eB[3]);                                  \
    PA = (half4_t){ (_Float16)eA[0], (_Float16)eA[1], (_Float16)eA[2], (_Float16)eA[3] }; \
    PB = (half4_t){ (_Float16)eB[0], (_Float16)eB[1], (_Float16)eB[2], (_Float16)eB[3] }; \
  }

// ---------------- flash attention: QBLK=32, key-split, fixed-shift softmax --
// grid = (128 q-tiles, KSPLIT), 512 thr = 8 waves = 8 heads. Two q-halves
// share K frags, V LDS stage, mask words, and barriers. Subtile-at-a-time
// QK+softmax keeps live VGPR state ~108 (R15's monolithic version spilled:
// 500 MB scratch traffic = the whole 163 us).
__global__ __launch_bounds__(512) void attn_kernel(
    const _Float16* __restrict__ Qh, const _Float16* __restrict__ Kh,
    const _Float16* __restrict__ Vt, const u64* __restrict__ pm,
    float* __restrict__ part, float* __restrict__ sbuf) {
  __shared__ _Float16 vlds[256 * 64];   // 32 KB
  const int tid = threadIdx.x;
  const int h = tid >> 6;
  const int lane = tid & 63;
  const int lq = lane & 15;
  const int lg = lane >> 4;
  const int q0 = blockIdx.x * QBLK;
  const int kb = blockIdx.y;
  const int k0 = kb * CHUNK;

  const half8_t qfA = *(const half8_t*)(Qh + ((size_t)h * NA + q0 + lq) * DH + lg * 8);
  const half8_t qfB = *(const half8_t*)(Qh + ((size_t)h * NA + q0 + 16 + lq) * DH + lg * 8);
  const _Float16* Kb = Kh + ((size_t)h * NA + k0) * DH;
  const u64* pmA = pm + (size_t)(q0 + lq) * 64 + kb * 16;
  const u64* pmB = pm + (size_t)(q0 + 16 + lq) * 64 + kb * 16;

  // V staging (block-cooperative, granule pre-swizzle keeps LDS linear)
  const int str = tid >> 3;
  const int gx = (tid & 7) ^ (str & 7);
  const _Float16* Vp0 = Vt + (size_t)str * NA + k0 + gx * 8;
  const int wr = str * 64 + (tid & 7) * 8;

  int ro[2][4];
#pragma unroll
  for (int u = 0; u < 2; ++u)
#pragma unroll
    for (int t = 0; t < 4; ++t)
      ro[u][t] = (h * DH + u * 16 + lq) * 64 +
                 (((2 * t + (lg >> 1)) ^ (lq & 7)) << 3) + (lg & 1) * 4;

  f32x4 z = {0.f, 0.f, 0.f, 0.f};
  f32x4 oA0 = z, oA1 = z, oB0 = z, oB1 = z;
  float srA = 0.f, srB = 0.f;

  for (int Gc = 0; Gc < 4; ++Gc) {
    u64x2 waA = *(const u64x2*)(pmA + Gc * 4);
    u64x2 wbA = *(const u64x2*)(pmA + Gc * 4 + 2);
    u64x2 waB = *(const u64x2*)(pmB + Gc * 4);
    u64x2 wbB = *(const u64x2*)(pmB + Gc * 4 + 2);
    const u64 w0A = waA[0], w1A = waA[1], w2A = wbA[0], w3A = wbA[1];
    const u64 w0B = waB[0], w1B = waB[1], w2B = wbB[0], w3B = wbB[1];
#pragma unroll
    for (int s = 0; s < 4; ++s) {
      const int kt = Gc * 256 + s * 64;
      // 1) V-stage loads early (latency hidden under QK+softmax)
      half8_t vg0 = *(const half8_t*)(Vp0 + kt);
      half8_t vg1 = *(const half8_t*)(Vp0 + (size_t)64 * NA + kt);
      half8_t vg2 = *(const half8_t*)(Vp0 + (size_t)128 * NA + kt);
      half8_t vg3 = *(const half8_t*)(Vp0 + (size_t)192 * NA + kt);

      // 2) subtile-at-a-time QK + softmax (bounded live state)
      half4_t pA0, pA1, pA2, pA3, pB0, pB1, pB2, pB3;
      QK_SUBTILE(0, pA0, pB0)
      QK_SUBTILE(1, pA1, pB1)
      QK_SUBTILE(2, pA2, pB2)
      QK_SUBTILE(3, pA3, pB3)

      // 3) commit V to LDS
      *(half8_t*)&vlds[wr]         = vg0;
      *(half8_t*)&vlds[wr + 4096]  = vg1;
      *(half8_t*)&vlds[wr + 8192]  = vg2;
      *(half8_t*)&vlds[wr + 12288] = vg3;
      __syncthreads();

      // 4) PV for both halves: V frags shared
      half4_t va, vb;
      va = *(const half4_t*)&vlds[ro[0][0]]; vb = *(const half4_t*)&vlds[ro[1][0]];
      oA0 = __builtin_amdgcn_mfma_f32_16x16x16f16(va, pA0, oA0, 0, 0, 0);
      oA1 = __builtin_amdgcn_mfma_f32_16x16x16f16(vb, pA0, oA1, 0, 0, 0);
      oB0 = __builtin_amdgcn_mfma_f32_16x16x16f16(va, pB0, oB0, 0, 0, 0);
      oB1 = __builtin_amdgcn_mfma_f32_16x16x16f16(vb, pB0, oB1, 0, 0, 0);
      va = *(const half4_t*)&vlds[ro[0][1]]; vb = *(const half4_t*)&vlds[ro[1][1]];
      oA0 = __builtin_amdgcn_mfma_f32_16x16x16f16(va, pA1, oA0, 0, 0, 0);
      oA1 = __builtin_amdgcn_mfma_f32_16x16x16f16(vb, pA1, oA1, 0, 0, 0);
      oB0 = __builtin_amdgcn_mfma_f32_16x16x16f16(va, pB1, oB0, 0, 0, 0);
      oB1 = __builtin_amdgcn_mfma_f32_16x16x16f16(vb, pB1, oB1, 0, 0, 0);
      va = *(const half4_t*)&vlds[ro[0][2]]; vb = *(const half4_t*)&vlds[ro[1][2]];
      oA0 = __builtin_amdgcn_mfma_f32_16x16x16f16(va, pA2, oA0, 0, 0, 0);
      oA1 = __builtin_amdgcn_mfma_f32_16x16x16f16(vb, pA2, oA1, 0, 0, 0);
      oB0 = __builtin_amdgcn_mfma_f32_16x16x16f16(va, pB2, oB0, 0, 0, 0);
      oB1 = __builtin_amdgcn_mfma_f32_16x16x16f16(vb, pB2, oB1, 0, 0, 0);
      va = *(const half4_t*)&vlds[ro[0][3]]; vb = *(const half4_t*)&vlds[ro[1][3]];
      oA0 = __builtin_amdgcn_mfma_f32_16x16x16f16(va, pA3, oA0, 0, 0, 0);
      oA1 = __builtin_amdgcn_mfma_f32_16x16x16f16(vb, pA3, oA1, 0, 0, 0);
      oB0 = __builtin_amdgcn_mfma_f32_16x16x16f16(va, pB3, oB0, 0, 0, 0);
      oB1 = __builtin_amdgcn_mfma_f32_16x16x16f16(vb, pB3, oB1, 0, 0, 0);
      __syncthreads();
    }
  }

  srA += __shfl_xor(srA, 16); srA += __shfl_xor(srA, 32);
  srB += __shfl_xor(srB, 16); srB += __shfl_xor(srB, 32);

  const int pb = (blockIdx.x * KSPLIT + kb) * NH + h;
  float* pp = part + (size_t)pb * 1024 + lane * 8;
  *(float4*)(pp)       = (float4){ oA0[0], oA0[1], oA0[2], oA0[3] };
  *(float4*)(pp + 4)   = (float4){ oA1[0], oA1[1], oA1[2], oA1[3] };
  *(float4*)(pp + 512) = (float4){ oB0[0], oB0[1], oB0[2], oB0[3] };
  *(float4*)(pp + 516) = (float4){ oB1[0], oB1[1], oB1[2], oB1[3] };
  if (lg == 0) {
    sbuf[pb * 32 + lq] = srA;
    sbuf[pb * 32 + 16 + lq] = srB;
  }
}

// ---------------- combine: plain sums over KSPLIT, both q-halves ------------
__global__ __launch_bounds__(256) void combine_kernel(
    const float* __restrict__ part, const float* __restrict__ sbuf,
    float* __restrict__ out) {
  const int wave = blockIdx.x * 4 + (threadIdx.x >> 6);  // qt*NH + h
  const int qt = wave >> 3;
  const int h = wave & 7;
  const int lane = threadIdx.x & 63;
  const int lq = lane & 15;
  const int lg = lane >> 4;

  float SA = 0.f, SB = 0.f;
  float4 A0 = {0,0,0,0}, A1 = {0,0,0,0}, B0 = {0,0,0,0}, B1 = {0,0,0,0};
#pragma unroll
  for (int kb = 0; kb < KSPLIT; kb++) {
    const int pb = (qt * KSPLIT + kb) * NH + h;
    const float* pp = part + (size_t)pb * 1024 + lane * 8;
    float4 a0 = *(const float4*)(pp);
    float4 a1 = *(const float4*)(pp + 4);
    float4 b0 = *(const float4*)(pp + 512);
    float4 b1 = *(const float4*)(pp + 516);
    SA += sbuf[pb * 32 + lq];
    SB += sbuf[pb * 32 + 16 + lq];
    A0.x += a0.x; A0.y += a0.y; A0.z += a0.z; A0.w += a0.w;
    A1.x += a1.x; A1.y += a1.y; A1.z += a1.z; A1.w += a1.w;
    B0.x += b0.x; B0.y += b0.y; B0.z += b0.z; B0.w += b0.w;
    B1.x += b1.x; B1.y += b1.y; B1.z += b1.z; B1.w += b1.w;
  }
  const float iA = 1.f / SA, iB = 1.f / SB;
  float* rowA = out + (size_t)(qt * QBLK + lq) * NF + h * DH;
  float* rowB = out + (size_t)(qt * QBLK + 16 + lq) * NF + h * DH;
  *(float4*)(rowA + lg * 4)      = (float4){ A0.x * iA, A0.y * iA, A0.z * iA, A0.w * iA };
  *(float4*)(rowA + 16 + lg * 4) = (float4){ A1.x * iA, A1.y * iA, A1.z * iA, A1.w * iA };
  *(float4*)(rowB + lg * 4)      = (float4){ B0.x * iB, B0.y * iB, B0.z * iB, B0.w * iB };
  *(float4*)(rowB + 16 + lg * 4) = (float4){ B1.x * iB, B1.y * iB, B1.z * iB, B1.w * iB };
}

extern "C" void kernel_launch(void* const* d_in, const int* in_sizes, int n_in,
                              void* d_out, int out_size, void* d_ws, size_t ws_size,
                              hipStream_t stream) {
  const float* x  = (const float*)d_in[0];
  const int* mask = (const int*)d_in[1];
  const float* Wq = (const float*)d_in[2];
  const float* bq = (const float*)d_in[3];
  const float* Wk = (const float*)d_in[4];
  const float* bk = (const float*)d_in[5];
  const float* Wv = (const float*)d_in[6];
  const float* bv = (const float*)d_in[7];
  float* out = (float*)d_out;

  char* ws = (char*)d_ws;   // ~25.7 MB
  u64* pm       = (u64*)(ws + 0);             // 2 MB
  _Float16* Qh  = (_Float16*)(ws + 2097152);  // [8][4096][32] f16, pre-scaled
  _Float16* Kh  = (_Float16*)(ws + 4194304);  // [8][4096][32] f16
  _Float16* Vt  = (_Float16*)(ws + 6291456);  // [256][4096] f16 (V^T)
  float* part   = (float*)(ws + 8388608);     // 16 MB
  float* sbuf   = (float*)(ws + 25165824);    // 512 KB

  proj_gemm<<<dim3(256, 12), 256, 0, stream>>>(x, Wq, Wk, Wv, bq, bk, bv,
                                               Qh, Kh, Vt);
  pack_mask<<<512, 512, 0, stream>>>(mask, pm);
  attn_kernel<<<dim3(NA / QBLK, KSPLIT), 512, 0, stream>>>(Qh, Kh, Vt, pm,
                                                           part, sbuf);
  combine_kernel<<<256, 256, 0, stream>>>(part, sbuf, out);
}